// Round 4
// baseline (320.252 us; speedup 1.0000x reference)
//
#include <hip/hip_runtime.h>
#include <math.h>

namespace {
constexpr int S = 7;
constexpr int PF = 30;   // floats per cell, predictions
constexpr int TF = 25;   // floats per cell, targets
constexpr int C = 20;
constexpr float EPS = 1e-6f;
constexpr float LAMBDA_COORD = 5.0f;
constexpr float LAMBDA_NOOBJ = 0.5f;
constexpr int BLK = 256;
constexpr int ILP = 4;
constexpr int NBLK = 1875;    // divisible by 15 -> grid stride == 0 mod 15 (hoisted lane roles)
constexpr int NBLK2 = 256;    // obj-phase grid

// d_ws layout (float indices)
constexpr int OFF_PART  = 0;                      // NBLK*4 floats (scan partials)
constexpr int OFF_PART2 = NBLK * 4;               // NBLK2*4 floats (obj partials)
constexpr int OFF_CNT   = OFF_PART2 + NBLK2 * 4;  // 1 int (worklist counter)
constexpr int OFF_WL    = OFF_CNT + 4;            // n_cells ints max (worklist)
}

__global__ void k_zero(int* cnt) {
    if (threadIdx.x == 0) *cnt = 0;
}

// ---------------- Phase A: stream ----------------
// pred: full float4 stream, conf^2 via hoisted lane-role masks.
// tgt: one 4B t4 load per cell; obj cells pushed to worklist.
__global__ __launch_bounds__(BLK) void k_scan(const float4* __restrict__ pred4,
                                              const float* __restrict__ tgt,
                                              float* __restrict__ part,
                                              int* __restrict__ cnt,
                                              int* __restrict__ wl,
                                              unsigned np4p, unsigned n_cells) {
    const unsigned tid = threadIdx.x;
    const unsigned stride = (unsigned)NBLK * BLK * ILP;   // == 0 mod 15
    const unsigned base0 = blockIdx.x * (unsigned)(BLK * ILP) + tid;

    float v2 = 0.f;

    // hoisted lane roles: q % 15 invariant across grid-stride iterations
    float mx[ILP], my[ILP], mz[ILP], mw[ILP];
    #pragma unroll
    for (int k = 0; k < ILP; ++k) {
        const unsigned r = (base0 + (unsigned)k * BLK) % 15u;
        mx[k] = (r == 1u) ? 1.f : 0.f;   // conf0 of even cell -> elem x
        my[k] = (r == 2u) ? 1.f : 0.f;   // conf1 of even cell -> elem y
        mz[k] = (r == 8u) ? 1.f : 0.f;   // conf0 of odd cell  -> elem z
        mw[k] = (r == 9u) ? 1.f : 0.f;   // conf1 of odd cell  -> elem w
    }
    for (unsigned s = base0; s < np4p; s += stride) {
        #pragma unroll
        for (int k = 0; k < ILP; ++k) {
            const unsigned idx = s + (unsigned)k * BLK;
            if (idx < np4p) {
                const float4 v = pred4[idx];
                v2 += (mx[k] * v.x) * v.x + (my[k] * v.y) * v.y
                    + (mz[k] * v.z) * v.z + (mw[k] * v.w) * v.w;
            }
        }
    }

    // t4 scan: coalesced-ish stride-100B scalar loads, 1 per cell
    const unsigned gstride = (unsigned)NBLK * BLK;
    for (unsigned cell = blockIdx.x * (unsigned)BLK + tid; cell < n_cells; cell += gstride) {
        const float t4 = tgt[cell * 25u + 4u];
        if (t4 > 0.f) {
            const int pos = atomicAdd(cnt, 1);
            wl[pos] = (int)cell;
        }
    }

    // reduce v2 -> part[blockIdx*4 + 2] (other 3 slots zero)
    #pragma unroll
    for (int off = 32; off >= 1; off >>= 1) v2 += __shfl_down(v2, off, 64);
    __shared__ float red[4];
    if ((tid & 63) == 0) red[tid >> 6] = v2;
    __syncthreads();
    if (tid < 4) {
        const float s2 = red[0] + red[1] + red[2] + red[3];
        part[blockIdx.x * 4 + tid] = (tid == 2) ? s2 : 0.f;
    }
}

// ---------------- Phase B: obj cells only (full lane utilization) ----------------
__global__ __launch_bounds__(BLK) void k_obj(const float* __restrict__ pred,
                                             const float* __restrict__ tgt,
                                             const int* __restrict__ cnt,
                                             const int* __restrict__ wl,
                                             float* __restrict__ part2) {
    const int tid = threadIdx.x;
    const int n = *cnt;
    float v0 = 0.f, v1 = 0.f, v2 = 0.f, v3 = 0.f;

    for (int w = blockIdx.x * BLK + tid; w < n; w += NBLK2 * BLK) {
        const unsigned cell = (unsigned)wl[w];
        const float* p = pred + (size_t)cell * PF;
        const float* t = tgt + (size_t)cell * TF;
        const unsigned j = cell % 7u;
        const unsigned i = (cell / 7u) % 7u;
        const float invS = 1.0f / 7.0f;

        const float2 p01 = *(const float2*)(p + 0);
        const float2 p23 = *(const float2*)(p + 2);
        const float2 p45 = *(const float2*)(p + 4);
        const float2 p67 = *(const float2*)(p + 6);
        const float2 p89 = *(const float2*)(p + 8);
        const float gx = t[0], gy = t[1], gw = t[2], gh = t[3];

        const float gcx = ((float)j + gx) * invS;
        const float gcy = ((float)i + gy) * invS;
        const float gx1 = gcx - gw * 0.5f, gy1 = gcy - gh * 0.5f;
        const float gx2 = gcx + gw * 0.5f, gy2 = gcy + gh * 0.5f;
        const float garea = (gx2 - gx1) * (gy2 - gy1);

        const float bx[2]  = {p01.x, p45.y};
        const float by[2]  = {p01.y, p67.x};
        const float bw_[2] = {p23.x, p67.y};
        const float bh[2]  = {p23.y, p89.x};
        const float cf[2]  = {p45.x, p89.y};
        float iou[2];
        #pragma unroll
        for (int b = 0; b < 2; ++b) {
            const float cx = ((float)j + bx[b]) * invS;
            const float cy = ((float)i + by[b]) * invS;
            const float x1 = cx - bw_[b] * 0.5f, y1 = cy - bh[b] * 0.5f;
            const float x2 = cx + bw_[b] * 0.5f, y2 = cy + bh[b] * 0.5f;
            const float ix1 = fmaxf(x1, gx1), iy1 = fmaxf(y1, gy1);
            const float ix2 = fminf(x2, gx2), iy2 = fminf(y2, gy2);
            const float inter = fmaxf(ix2 - ix1, 0.f) * fmaxf(iy2 - iy1, 0.f);
            const float parea = (x2 - x1) * (y2 - y1);
            iou[b] = inter / (parea + garea - inter + EPS);
        }
        const int best = (iou[1] > iou[0]) ? 1 : 0;   // first max wins
        const float rconf = cf[best], riou = iou[best];

        const float dx = bx[best] - gx, dy = by[best] - gy;
        const float swd = sqrtf(bw_[best] + EPS) - sqrtf(gw + EPS);
        const float shd = sqrtf(bh[best] + EPS) - sqrtf(gh + EPS);
        v0 += dx * dx + dy * dy + swd * swd + shd * shd;
        const float dc = rconf - riou;
        v1 += dc * dc;
        v2 -= rconf * rconf;    // subtract responsible box from noobj sum

        float se = 0.f, dot = 0.f, sg = 0.f;
        #pragma unroll
        for (int c = 0; c < C; c += 2) {
            const float2 lc = *(const float2*)(p + 10 + c);
            const float g0 = t[5 + c], g1 = t[6 + c];
            se  += __expf(lc.x) + __expf(lc.y);
            dot += g0 * lc.x + g1 * lc.y;
            sg  += g0 + g1;
        }
        v3 += __logf(se) * sg - dot;
    }

    float v[4] = {v0, v1, v2, v3};
    #pragma unroll
    for (int off = 32; off >= 1; off >>= 1) {
        v[0] += __shfl_down(v[0], off, 64);
        v[1] += __shfl_down(v[1], off, 64);
        v[2] += __shfl_down(v[2], off, 64);
        v[3] += __shfl_down(v[3], off, 64);
    }
    __shared__ float red[16];
    if ((tid & 63) == 0) {
        const int wv = tid >> 6;
        red[wv * 4 + 0] = v[0];
        red[wv * 4 + 1] = v[1];
        red[wv * 4 + 2] = v[2];
        red[wv * 4 + 3] = v[3];
    }
    __syncthreads();
    if (tid < 4)
        part2[blockIdx.x * 4 + tid] =
            red[tid] + red[4 + tid] + red[8 + tid] + red[12 + tid];
}

// ---------------- Finalize ----------------
__global__ __launch_bounds__(BLK) void k_fin(const float* __restrict__ part,
                                             float* __restrict__ out,
                                             int nslots, float n) {
    const int tid = threadIdx.x;
    float a0 = 0.f, a1 = 0.f, a2 = 0.f, a3 = 0.f;
    for (int r = tid; r < nslots; r += BLK) {
        const float4 q = *(const float4*)(part + r * 4);
        a0 += q.x; a1 += q.y; a2 += q.z; a3 += q.w;
    }
    float v[4] = {a0, a1, a2, a3};
    #pragma unroll
    for (int off = 32; off >= 1; off >>= 1) {
        v[0] += __shfl_down(v[0], off, 64);
        v[1] += __shfl_down(v[1], off, 64);
        v[2] += __shfl_down(v[2], off, 64);
        v[3] += __shfl_down(v[3], off, 64);
    }
    __shared__ float red[16];
    if ((tid & 63) == 0) {
        const int wv = tid >> 6;
        red[wv * 4 + 0] = v[0];
        red[wv * 4 + 1] = v[1];
        red[wv * 4 + 2] = v[2];
        red[wv * 4 + 3] = v[3];
    }
    __syncthreads();
    if (tid == 0) {
        const float coord  = red[0] + red[4] + red[8] + red[12];
        const float cobj   = red[1] + red[5] + red[9] + red[13];
        const float cnoobj = red[2] + red[6] + red[10] + red[14];
        const float ccls   = red[3] + red[7] + red[11] + red[15];
        const float inv = 1.0f / n;
        out[0] = coord * inv;
        out[1] = cobj * inv;
        out[2] = cnoobj * inv;
        out[3] = ccls * inv;
        out[4] = (LAMBDA_COORD * coord + cobj + LAMBDA_NOOBJ * cnoobj + ccls) * inv;
    }
}

// ---------------- Fallback (known-good R2 kernel, used only if ws too small) ----
__global__ __launch_bounds__(BLK) void k_main_fb(const float* __restrict__ pred,
                                                 const float* __restrict__ tgt,
                                                 float* __restrict__ part,
                                                 int n_cells) {
    const int tid = threadIdx.x;
    const int cell = blockIdx.x * BLK + tid;
    float v0 = 0.f, v1 = 0.f, v2 = 0.f, v3 = 0.f;
    if (cell < n_cells) {
        const float* p = pred + (size_t)cell * PF;
        const float* t = tgt + (size_t)cell * TF;
        const float2 p45 = *(const float2*)(p + 4);
        const float2 p89 = *(const float2*)(p + 8);
        const float c0 = p45.x, c1 = p89.y;
        v2 = c0 * c0 + c1 * c1;
        if (t[4] > 0.f) {
            const int j = cell % S;
            const int i = (cell / S) % S;
            const float invS = 1.0f / (float)S;
            const float2 p01 = *(const float2*)(p + 0);
            const float2 p23 = *(const float2*)(p + 2);
            const float2 p67 = *(const float2*)(p + 6);
            const float gx = t[0], gy = t[1], gw = t[2], gh = t[3];
            const float gcx = ((float)j + gx) * invS;
            const float gcy = ((float)i + gy) * invS;
            const float gx1 = gcx - gw * 0.5f, gy1 = gcy - gh * 0.5f;
            const float gx2 = gcx + gw * 0.5f, gy2 = gcy + gh * 0.5f;
            const float garea = (gx2 - gx1) * (gy2 - gy1);
            const float bx[2]  = {p01.x, p45.y};
            const float by[2]  = {p01.y, p67.x};
            const float bw_[2] = {p23.x, p67.y};
            const float bh[2]  = {p23.y, p89.x};
            const float cf[2]  = {c0, c1};
            float iou[2];
            #pragma unroll
            for (int b = 0; b < 2; ++b) {
                const float cx = ((float)j + bx[b]) * invS;
                const float cy = ((float)i + by[b]) * invS;
                const float x1 = cx - bw_[b] * 0.5f, y1 = cy - bh[b] * 0.5f;
                const float x2 = cx + bw_[b] * 0.5f, y2 = cy + bh[b] * 0.5f;
                const float ix1 = fmaxf(x1, gx1), iy1 = fmaxf(y1, gy1);
                const float ix2 = fminf(x2, gx2), iy2 = fminf(y2, gy2);
                const float inter = fmaxf(ix2 - ix1, 0.f) * fmaxf(iy2 - iy1, 0.f);
                const float parea = (x2 - x1) * (y2 - y1);
                iou[b] = inter / (parea + garea - inter + EPS);
            }
            const int best = (iou[1] > iou[0]) ? 1 : 0;
            const float rconf = cf[best], riou = iou[best];
            const float dx = bx[best] - gx, dy = by[best] - gy;
            const float swd = sqrtf(bw_[best] + EPS) - sqrtf(gw + EPS);
            const float shd = sqrtf(bh[best] + EPS) - sqrtf(gh + EPS);
            v0 = dx*dx + dy*dy + swd*swd + shd*shd;
            const float dc = rconf - riou;
            v1 = dc * dc;
            v2 -= rconf * rconf;
            float se = 0.f, dot = 0.f, sg = 0.f;
            #pragma unroll
            for (int c = 0; c < C; c += 2) {
                const float2 lc = *(const float2*)(p + 10 + c);
                const float g0 = t[5 + c], g1 = t[6 + c];
                se  += __expf(lc.x) + __expf(lc.y);
                dot += g0 * lc.x + g1 * lc.y;
                sg  += g0 + g1;
            }
            v3 = __logf(se) * sg - dot;
        }
    }
    float v[4] = {v0, v1, v2, v3};
    #pragma unroll
    for (int off = 32; off >= 1; off >>= 1) {
        v[0] += __shfl_down(v[0], off, 64);
        v[1] += __shfl_down(v[1], off, 64);
        v[2] += __shfl_down(v[2], off, 64);
        v[3] += __shfl_down(v[3], off, 64);
    }
    __shared__ float red[16];
    if ((tid & 63) == 0) {
        const int wv = tid >> 6;
        red[wv * 4 + 0] = v[0];
        red[wv * 4 + 1] = v[1];
        red[wv * 4 + 2] = v[2];
        red[wv * 4 + 3] = v[3];
    }
    __syncthreads();
    if (tid < 4)
        part[blockIdx.x * 4 + tid] =
            red[tid] + red[4 + tid] + red[8 + tid] + red[12 + tid];
}

extern "C" void kernel_launch(void* const* d_in, const int* in_sizes, int n_in,
                              void* d_out, int out_size, void* d_ws, size_t ws_size,
                              hipStream_t stream) {
    const float* pred = (const float*)d_in[0];
    const float* tgt  = (const float*)d_in[1];
    float* out = (float*)d_out;
    float* ws  = (float*)d_ws;

    const int n_cells = in_sizes[0] / PF;                 // 802816
    const unsigned np4p = (unsigned)(in_sizes[0] / 4);    // pred float4 count
    const float bs = (float)(n_cells / (S * S));          // 16384

    const size_t need = (size_t)(OFF_WL + n_cells) * sizeof(float);
    if (ws_size >= need) {
        float* part  = ws + OFF_PART;
        float* part2 = ws + OFF_PART2;
        int*   cnt   = (int*)(ws + OFF_CNT);
        int*   wl    = (int*)(ws + OFF_WL);
        k_zero<<<1, 64, 0, stream>>>(cnt);
        k_scan<<<NBLK, BLK, 0, stream>>>((const float4*)pred, tgt, part, cnt, wl,
                                         np4p, (unsigned)n_cells);
        k_obj<<<NBLK2, BLK, 0, stream>>>(pred, tgt, cnt, wl, part2);
        k_fin<<<1, BLK, 0, stream>>>(part, out, NBLK + NBLK2, bs);
    } else {
        // known-good R2 path (ws needs only 50 KB)
        const int nblk = (n_cells + BLK - 1) / BLK;       // 3136
        k_main_fb<<<nblk, BLK, 0, stream>>>(pred, tgt, ws, n_cells);
        k_fin<<<1, BLK, 0, stream>>>(ws, out, nblk, bs);
    }
}

// Round 5
// 213.545 us; speedup vs baseline: 1.4997x; 1.4997x over previous
//
#include <hip/hip_runtime.h>
#include <math.h>

namespace {
constexpr int S = 7;
constexpr int PF = 30;   // floats per cell, predictions
constexpr int TF = 25;   // floats per cell, targets
constexpr int C = 20;
constexpr float EPS = 1e-6f;
constexpr float LAMBDA_COORD = 5.0f;
constexpr float LAMBDA_NOOBJ = 0.5f;
constexpr int BLK = 256;
constexpr int CPT = 4;   // cells per thread (batched independent loads)
}

// One thread processes CPT cells. Phase 1 issues 3*CPT independent loads
// (conf pair x2 + t4 per cell) before any use -> ~4x in-flight misses vs R2.
// Phase 2 accumulates; ~6% obj cells take the heavy branch (lines cache-hot).
__global__ __launch_bounds__(BLK) void k_main(const float* __restrict__ pred,
                                              const float* __restrict__ tgt,
                                              float* __restrict__ part,
                                              int n_cells) {
    const int tid = threadIdx.x;
    const int base = blockIdx.x * (BLK * CPT) + tid;

    // ---- phase 1: batched independent loads ----
    float2 a45[CPT], a89[CPT];
    float t4[CPT];
    bool ok[CPT];
    #pragma unroll
    for (int k = 0; k < CPT; ++k) {
        const int cell = base + k * BLK;
        ok[k] = (cell < n_cells);
        const float* p = pred + (size_t)cell * PF;
        const float* t = tgt + (size_t)cell * TF;
        if (ok[k]) {
            a45[k] = *(const float2*)(p + 4);   // (c0, x1)
            a89[k] = *(const float2*)(p + 8);   // (h1, c1)
            t4[k]  = t[4];
        } else {
            a45[k] = make_float2(0.f, 0.f);
            a89[k] = make_float2(0.f, 0.f);
            t4[k]  = 0.f;
        }
    }

    // ---- phase 2: accumulate ----
    float v0 = 0.f, v1 = 0.f, v2 = 0.f, v3 = 0.f;
    #pragma unroll
    for (int k = 0; k < CPT; ++k) {
        const float c0 = a45[k].x, c1 = a89[k].y;
        v2 += c0 * c0 + c1 * c1;

        if (t4[k] > 0.f) {                       // ~6% of lanes per k
            const int cell = base + k * BLK;
            const float* p = pred + (size_t)cell * PF;
            const float* t = tgt + (size_t)cell * TF;
            const int j = cell % S;
            const int i = (cell / S) % S;
            const float invS = 1.0f / (float)S;

            const float2 p01 = *(const float2*)(p + 0);
            const float2 p23 = *(const float2*)(p + 2);
            const float2 p67 = *(const float2*)(p + 6);
            const float gx = t[0], gy = t[1], gw = t[2], gh = t[3];

            const float gcx = ((float)j + gx) * invS;
            const float gcy = ((float)i + gy) * invS;
            const float gx1 = gcx - gw * 0.5f, gy1 = gcy - gh * 0.5f;
            const float gx2 = gcx + gw * 0.5f, gy2 = gcy + gh * 0.5f;
            const float garea = (gx2 - gx1) * (gy2 - gy1);

            const float bx[2]  = {p01.x, a45[k].y};
            const float by[2]  = {p01.y, p67.x};
            const float bw_[2] = {p23.x, p67.y};
            const float bh[2]  = {p23.y, a89[k].x};
            const float cf[2]  = {c0, c1};
            float iou[2];
            #pragma unroll
            for (int b = 0; b < 2; ++b) {
                const float cx = ((float)j + bx[b]) * invS;
                const float cy = ((float)i + by[b]) * invS;
                const float x1 = cx - bw_[b] * 0.5f, y1 = cy - bh[b] * 0.5f;
                const float x2 = cx + bw_[b] * 0.5f, y2 = cy + bh[b] * 0.5f;
                const float ix1 = fmaxf(x1, gx1), iy1 = fmaxf(y1, gy1);
                const float ix2 = fminf(x2, gx2), iy2 = fminf(y2, gy2);
                const float inter = fmaxf(ix2 - ix1, 0.f) * fmaxf(iy2 - iy1, 0.f);
                const float parea = (x2 - x1) * (y2 - y1);
                iou[b] = inter / (parea + garea - inter + EPS);
            }
            const int best = (iou[1] > iou[0]) ? 1 : 0;   // first max wins
            const float rconf = cf[best], riou = iou[best];

            const float dx = bx[best] - gx, dy = by[best] - gy;
            const float swd = sqrtf(bw_[best] + EPS) - sqrtf(gw + EPS);
            const float shd = sqrtf(bh[best] + EPS) - sqrtf(gh + EPS);
            v0 += dx * dx + dy * dy + swd * swd + shd * shd;
            const float dc = rconf - riou;
            v1 += dc * dc;
            v2 -= rconf * rconf;

            float se = 0.f, dot = 0.f, sg = 0.f;
            #pragma unroll
            for (int c = 0; c < C; c += 2) {
                const float2 lc = *(const float2*)(p + 10 + c);
                const float g0 = t[5 + c], g1 = t[6 + c];
                se  += __expf(lc.x) + __expf(lc.y);
                dot += g0 * lc.x + g1 * lc.y;
                sg  += g0 + g1;
            }
            v3 += __logf(se) * sg - dot;
        }
    }

    // ---- reduce: wave64 butterfly -> LDS -> per-block partial slot ----
    float v[4] = {v0, v1, v2, v3};
    #pragma unroll
    for (int off = 32; off >= 1; off >>= 1) {
        v[0] += __shfl_down(v[0], off, 64);
        v[1] += __shfl_down(v[1], off, 64);
        v[2] += __shfl_down(v[2], off, 64);
        v[3] += __shfl_down(v[3], off, 64);
    }
    __shared__ float red[16];
    if ((tid & 63) == 0) {
        const int wv = tid >> 6;
        red[wv * 4 + 0] = v[0];
        red[wv * 4 + 1] = v[1];
        red[wv * 4 + 2] = v[2];
        red[wv * 4 + 3] = v[3];
    }
    __syncthreads();
    if (tid < 4)
        part[blockIdx.x * 4 + tid] =
            red[tid] + red[4 + tid] + red[8 + tid] + red[12 + tid];
}

// Single block: reduce nblk x 4 partials, write 5 outputs.
__global__ __launch_bounds__(BLK) void k_fin(const float* __restrict__ part,
                                             float* __restrict__ out,
                                             int nblk, float n) {
    const int tid = threadIdx.x;
    float a0 = 0.f, a1 = 0.f, a2 = 0.f, a3 = 0.f;
    for (int r = tid; r < nblk; r += BLK) {
        const float4 q = *(const float4*)(part + r * 4);
        a0 += q.x; a1 += q.y; a2 += q.z; a3 += q.w;
    }
    float v[4] = {a0, a1, a2, a3};
    #pragma unroll
    for (int off = 32; off >= 1; off >>= 1) {
        v[0] += __shfl_down(v[0], off, 64);
        v[1] += __shfl_down(v[1], off, 64);
        v[2] += __shfl_down(v[2], off, 64);
        v[3] += __shfl_down(v[3], off, 64);
    }
    __shared__ float red[16];
    if ((tid & 63) == 0) {
        const int wv = tid >> 6;
        red[wv * 4 + 0] = v[0];
        red[wv * 4 + 1] = v[1];
        red[wv * 4 + 2] = v[2];
        red[wv * 4 + 3] = v[3];
    }
    __syncthreads();
    if (tid == 0) {
        const float coord  = red[0] + red[4] + red[8] + red[12];
        const float cobj   = red[1] + red[5] + red[9] + red[13];
        const float cnoobj = red[2] + red[6] + red[10] + red[14];
        const float ccls   = red[3] + red[7] + red[11] + red[15];
        const float inv = 1.0f / n;
        out[0] = coord * inv;
        out[1] = cobj * inv;
        out[2] = cnoobj * inv;
        out[3] = ccls * inv;
        out[4] = (LAMBDA_COORD * coord + cobj + LAMBDA_NOOBJ * cnoobj + ccls) * inv;
    }
}

extern "C" void kernel_launch(void* const* d_in, const int* in_sizes, int n_in,
                              void* d_out, int out_size, void* d_ws, size_t ws_size,
                              hipStream_t stream) {
    const float* pred = (const float*)d_in[0];
    const float* tgt  = (const float*)d_in[1];
    float* out  = (float*)d_out;
    float* part = (float*)d_ws;

    const int n_cells = in_sizes[0] / PF;                   // 802816
    const float bs = (float)(n_cells / (S * S));            // 16384
    const int nblk = (n_cells + BLK * CPT - 1) / (BLK * CPT);   // 784

    k_main<<<nblk, BLK, 0, stream>>>(pred, tgt, part, n_cells);
    k_fin<<<1, BLK, 0, stream>>>(part, out, nblk, bs);
}

// Round 6
// 205.632 us; speedup vs baseline: 1.5574x; 1.0385x over previous
//
#include <hip/hip_runtime.h>
#include <math.h>

namespace {
constexpr int S = 7;
constexpr int PF = 30;   // floats per cell, predictions
constexpr int TF = 25;   // floats per cell, targets
constexpr int C = 20;
constexpr float EPS = 1e-6f;
constexpr float LAMBDA_COORD = 5.0f;
constexpr float LAMBDA_NOOBJ = 0.5f;
constexpr int BLK = 256;
constexpr int TILE_F4 = BLK * PF / 4;   // 1920 float4 per block tile
}

// Dense-stream design: per block, stage 256 cells x 30 floats of pred into
// LDS via coalesced float4 (7.5/thread, independent). One scattered 4B t4
// per thread issued BEFORE staging (latency hides under stream). All pred
// element access then comes from LDS; obj lanes read tgt from hot L2.
__global__ __launch_bounds__(BLK) void k_main(const float4* __restrict__ pred4,
                                              const float* __restrict__ tgt,
                                              float* __restrict__ part,
                                              int n_cells) {
    __shared__ float sp[BLK * PF];   // 30720 B -> 5 blocks/CU
    const int tid = threadIdx.x;
    const int cell = blockIdx.x * BLK + tid;
    const bool ok = cell < n_cells;

    // scattered t4 first (independent of staging)
    const float t4 = ok ? tgt[(size_t)cell * TF + 4] : 0.f;

    // dense coalesced staging of the block's pred tile
    {
        const size_t base4 = (size_t)blockIdx.x * TILE_F4;
        float4* s4 = (float4*)sp;
        #pragma unroll
        for (int k = 0; k < 8; ++k) {
            const int idx = tid + k * BLK;
            if (idx < TILE_F4) s4[idx] = pred4[base4 + idx];
        }
    }
    __syncthreads();

    float v0 = 0.f, v1 = 0.f, v2 = 0.f, v3 = 0.f;
    if (ok) {
        const float* p = sp + tid * PF;      // this thread's cell in LDS
        const float c0 = p[4], c1 = p[9];
        v2 = c0 * c0 + c1 * c1;

        if (t4 > 0.f) {                      // ~6% of lanes
            const float* t = tgt + (size_t)cell * TF;   // lines hot in L2
            const int j = cell % S;
            const int i = (cell / S) % S;
            const float invS = 1.0f / (float)S;

            const float gx = t[0], gy = t[1], gw = t[2], gh = t[3];
            const float gcx = ((float)j + gx) * invS;
            const float gcy = ((float)i + gy) * invS;
            const float gx1 = gcx - gw * 0.5f, gy1 = gcy - gh * 0.5f;
            const float gx2 = gcx + gw * 0.5f, gy2 = gcy + gh * 0.5f;
            const float garea = (gx2 - gx1) * (gy2 - gy1);

            const float bx[2]  = {p[0], p[5]};
            const float by[2]  = {p[1], p[6]};
            const float bw_[2] = {p[2], p[7]};
            const float bh[2]  = {p[3], p[8]};
            const float cf[2]  = {c0, c1};
            float iou[2];
            #pragma unroll
            for (int b = 0; b < 2; ++b) {
                const float cx = ((float)j + bx[b]) * invS;
                const float cy = ((float)i + by[b]) * invS;
                const float x1 = cx - bw_[b] * 0.5f, y1 = cy - bh[b] * 0.5f;
                const float x2 = cx + bw_[b] * 0.5f, y2 = cy + bh[b] * 0.5f;
                const float ix1 = fmaxf(x1, gx1), iy1 = fmaxf(y1, gy1);
                const float ix2 = fminf(x2, gx2), iy2 = fminf(y2, gy2);
                const float inter = fmaxf(ix2 - ix1, 0.f) * fmaxf(iy2 - iy1, 0.f);
                const float parea = (x2 - x1) * (y2 - y1);
                iou[b] = inter / (parea + garea - inter + EPS);
            }
            const int best = (iou[1] > iou[0]) ? 1 : 0;   // first max wins
            const float rconf = cf[best], riou = iou[best];

            const float dx = bx[best] - gx, dy = by[best] - gy;
            const float swd = sqrtf(bw_[best] + EPS) - sqrtf(gw + EPS);
            const float shd = sqrtf(bh[best] + EPS) - sqrtf(gh + EPS);
            v0 = dx * dx + dy * dy + swd * swd + shd * shd;
            const float dc = rconf - riou;
            v1 = dc * dc;
            v2 -= rconf * rconf;

            float se = 0.f, dot = 0.f, sg = 0.f;
            #pragma unroll
            for (int c = 0; c < C; c += 2) {
                const float l0 = p[10 + c], l1 = p[11 + c];
                const float g0 = t[5 + c],  g1 = t[6 + c];
                se  += __expf(l0) + __expf(l1);
                dot += g0 * l0 + g1 * l1;
                sg  += g0 + g1;
            }
            v3 = __logf(se) * sg - dot;
        }
    }

    // ---- reduce: wave64 butterfly -> LDS -> per-block partial slot ----
    float v[4] = {v0, v1, v2, v3};
    #pragma unroll
    for (int off = 32; off >= 1; off >>= 1) {
        v[0] += __shfl_down(v[0], off, 64);
        v[1] += __shfl_down(v[1], off, 64);
        v[2] += __shfl_down(v[2], off, 64);
        v[3] += __shfl_down(v[3], off, 64);
    }
    __syncthreads();                    // done with sp; reuse for reduction
    if ((tid & 63) == 0) {
        const int wv = tid >> 6;
        sp[wv * 4 + 0] = v[0];
        sp[wv * 4 + 1] = v[1];
        sp[wv * 4 + 2] = v[2];
        sp[wv * 4 + 3] = v[3];
    }
    __syncthreads();
    if (tid < 4)
        part[blockIdx.x * 4 + tid] =
            sp[tid] + sp[4 + tid] + sp[8 + tid] + sp[12 + tid];
}

// Single block: reduce nblk x 4 partials, write 5 outputs.
__global__ __launch_bounds__(BLK) void k_fin(const float* __restrict__ part,
                                             float* __restrict__ out,
                                             int nblk, float n) {
    const int tid = threadIdx.x;
    float a0 = 0.f, a1 = 0.f, a2 = 0.f, a3 = 0.f;
    for (int r = tid; r < nblk; r += BLK) {
        const float4 q = *(const float4*)(part + r * 4);
        a0 += q.x; a1 += q.y; a2 += q.z; a3 += q.w;
    }
    float v[4] = {a0, a1, a2, a3};
    #pragma unroll
    for (int off = 32; off >= 1; off >>= 1) {
        v[0] += __shfl_down(v[0], off, 64);
        v[1] += __shfl_down(v[1], off, 64);
        v[2] += __shfl_down(v[2], off, 64);
        v[3] += __shfl_down(v[3], off, 64);
    }
    __shared__ float red[16];
    if ((tid & 63) == 0) {
        const int wv = tid >> 6;
        red[wv * 4 + 0] = v[0];
        red[wv * 4 + 1] = v[1];
        red[wv * 4 + 2] = v[2];
        red[wv * 4 + 3] = v[3];
    }
    __syncthreads();
    if (tid == 0) {
        const float coord  = red[0] + red[4] + red[8] + red[12];
        const float cobj   = red[1] + red[5] + red[9] + red[13];
        const float cnoobj = red[2] + red[6] + red[10] + red[14];
        const float ccls   = red[3] + red[7] + red[11] + red[15];
        const float inv = 1.0f / n;
        out[0] = coord * inv;
        out[1] = cobj * inv;
        out[2] = cnoobj * inv;
        out[3] = ccls * inv;
        out[4] = (LAMBDA_COORD * coord + cobj + LAMBDA_NOOBJ * cnoobj + ccls) * inv;
    }
}

extern "C" void kernel_launch(void* const* d_in, const int* in_sizes, int n_in,
                              void* d_out, int out_size, void* d_ws, size_t ws_size,
                              hipStream_t stream) {
    const float* pred = (const float*)d_in[0];
    const float* tgt  = (const float*)d_in[1];
    float* out  = (float*)d_out;
    float* part = (float*)d_ws;

    const int n_cells = in_sizes[0] / PF;              // 802816
    const float bs = (float)(n_cells / (S * S));       // 16384
    const int nblk = (n_cells + BLK - 1) / BLK;        // 3136

    k_main<<<nblk, BLK, 0, stream>>>((const float4*)pred, tgt, part, n_cells);
    k_fin<<<1, BLK, 0, stream>>>(part, out, nblk, bs);
}